// Round 3
// baseline (45.513 us; speedup 1.0000x reference)
//
#include <hip/hip_runtime.h>
#include <math.h>

namespace {

constexpr int kN = 8;
constexpr int kBatch = 500000;
constexpr int kNPairs = 28;        // 8*7/2
constexpr int kRowsPerThread = 2;
constexpr int kRowsPerBlock = 256 * kRowsPerThread;  // 512
constexpr int kBlocks = (kBatch + kRowsPerBlock - 1) / kRowsPerBlock;  // 977
constexpr double kScale = 4294967296.0;  // 2^32 fixed-point scale

// Replicates the torch/jax sample_index ordering:
// gaps 2..7 first (each gap g: j=0..N-1-g), then adjacent pairs (j,j+1) at 21..27.
constexpr int pair_index(int a, int b) {
  const int gap = b - a;
  if (gap == 1) return 21 + a;
  int start = 0;
  for (int g = 2; g < gap; ++g) start += kN - g;
  return start + a;
}

// DFS over increasing element sequences. Each extension adds one chain-pair
// value; every sequence of size >= 3 contributes |x[pair(F,last)] - chain|.
// All indices compile-time -> x[] and sa[] stay fully in registers.
// sa[] rotation by (F+SIZE) breaks the serial accumulation chain 4-ways.
template <int F, int LAST, int SIZE, int NEXT>
__device__ __forceinline__ void dfs(const float* x, float chain, float (&sa)[4]) {
  if constexpr (NEXT < kN) {
    const float c2 = chain + x[pair_index(LAST, NEXT)];
    if constexpr (SIZE + 1 >= 3) {
      sa[(F + SIZE + 1) & 3] += fabsf(x[pair_index(F, NEXT)] - c2);
    }
    dfs<F, NEXT, SIZE + 1, NEXT + 1>(x, c2, sa);  // extend through NEXT
    dfs<F, LAST, SIZE, NEXT + 1>(x, chain, sa);   // skip NEXT
  }
}

__device__ __forceinline__ float row_loss(const float* __restrict__ rowp) {
  float x[kNPairs];
  const float4* p = reinterpret_cast<const float4*>(rowp);
#pragma unroll
  for (int j = 0; j < 7; ++j) {
    const float4 t = p[j];
    x[4 * j + 0] = t.x;
    x[4 * j + 1] = t.y;
    x[4 * j + 2] = t.z;
    x[4 * j + 3] = t.w;
  }
  // A-part: adjacent pairs live at slots 21..27 (two accumulators for ILP)
  float se0 = 0.0f, se1 = 0.0f;
#pragma unroll
  for (int k = 21; k < 28; ++k) {
    if (k & 1) se0 += __expf(-x[k]); else se1 += __expf(-x[k]);
  }
  // B-part: 219 combinatorial residuals via shared-chain DFS (247 adds total)
  float sa[4] = {0.0f, 0.0f, 0.0f, 0.0f};
  dfs<0, 0, 1, 1>(x, 0.0f, sa);
  dfs<1, 1, 1, 2>(x, 0.0f, sa);
  dfs<2, 2, 1, 3>(x, 0.0f, sa);
  dfs<3, 3, 1, 4>(x, 0.0f, sa);
  dfs<4, 4, 1, 5>(x, 0.0f, sa);
  dfs<5, 5, 1, 6>(x, 0.0f, sa);
  return (0.5f / 7.0f) * (se0 + se1) +
         (0.5f / 219.0f) * ((sa[0] + sa[1]) + (sa[2] + sa[3]));
}

__global__ __launch_bounds__(256) void arc_fused(const float* __restrict__ in,
                                                 unsigned long long* __restrict__ acc,
                                                 unsigned int* __restrict__ cnt,
                                                 float* __restrict__ out) {
  const int tid = threadIdx.x;
  const int base = blockIdx.x * kRowsPerBlock;

  float v0 = 0.0f, v1 = 0.0f;
  const int r0 = base + tid;
  const int r1 = r0 + 256;
  if (r0 < kBatch) v0 = row_loss(in + (size_t)r0 * kNPairs);
  if (r1 < kBatch) v1 = row_loss(in + (size_t)r1 * kNPairs);
  float v = v0 + v1;

  // wave (64-lane) shuffle reduce, then cross-wave LDS reduce
#pragma unroll
  for (int off = 32; off > 0; off >>= 1) v += __shfl_down(v, off, 64);
  __shared__ float red[4];
  const int lane = tid & 63;
  const int wid = tid >> 6;
  if (lane == 0) red[wid] = v;
  __syncthreads();

  if (tid == 0) {
    const double d = (double)red[0] + (double)red[1] + (double)red[2] + (double)red[3];
    // Fixed-point block contribution: integer atomics commute -> deterministic.
    const unsigned long long q = (unsigned long long)__double2ll_rn(d * kScale);
    atomicAdd(acc, q);
    __threadfence();                       // acc-add visible before cnt-add
    const unsigned int old = atomicAdd(cnt, 1u);
    if (old == (unsigned int)(gridDim.x - 1)) {
      __threadfence();
      const unsigned long long total = atomicAdd(acc, 0ULL);  // atomic read
      out[0] = (float)((double)total / (kScale * (double)kBatch));
    }
  }
}

}  // namespace

extern "C" void kernel_launch(void* const* d_in, const int* in_sizes, int n_in,
                              void* d_out, int out_size, void* d_ws, size_t ws_size,
                              hipStream_t stream) {
  const float* in = (const float*)d_in[0];
  float* out = (float*)d_out;
  unsigned long long* acc = (unsigned long long*)d_ws;          // 8 B
  unsigned int* cnt = (unsigned int*)((char*)d_ws + 8);          // 4 B
  // Re-zero the atomics every launch (graph-capturable async memset).
  hipMemsetAsync(d_ws, 0, 16, stream);
  arc_fused<<<kBlocks, 256, 0, stream>>>(in, acc, cnt, out);
}

// Round 4
// 21.147 us; speedup vs baseline: 2.1522x; 2.1522x over previous
//
#include <hip/hip_runtime.h>
#include <math.h>

namespace {

constexpr int kN = 8;
constexpr int kBatch = 500000;
constexpr int kNPairs = 28;  // 8*7/2

// Replicates the torch/jax sample_index ordering:
// gaps 2..7 first (each gap g: j=0..N-1-g), then adjacent pairs (j,j+1) at 21..27.
constexpr int pair_index(int a, int b) {
  const int gap = b - a;
  if (gap == 1) return 21 + a;
  int start = 0;
  for (int g = 2; g < gap; ++g) start += kN - g;
  return start + a;
}

// DFS over increasing element sequences. Each extension adds one chain-pair
// value; every sequence of size >= 3 contributes |x[pair(F,last)] - chain|.
// All indices compile-time -> x[] and sa[] stay fully in registers.
// sa[] rotation breaks the serial accumulation chain 4-ways.
template <int F, int LAST, int SIZE, int NEXT>
__device__ __forceinline__ void dfs(const float* x, float chain, float (&sa)[4]) {
  if constexpr (NEXT < kN) {
    const float c2 = chain + x[pair_index(LAST, NEXT)];
    if constexpr (SIZE + 1 >= 3) {
      sa[(F + SIZE + 1) & 3] += fabsf(x[pair_index(F, NEXT)] - c2);
    }
    dfs<F, NEXT, SIZE + 1, NEXT + 1>(x, c2, sa);  // extend through NEXT
    dfs<F, LAST, SIZE, NEXT + 1>(x, chain, sa);   // skip NEXT
  }
}

// __launch_bounds__(256, 4): 4 waves/EU -> ~128-VGPR budget. At the default
// the allocator squeezed this kernel to 28 VGPRs (R3 counters) and serialized
// the DFS; we want all 28 row values + accumulators live and 7 loads in flight.
__global__ __launch_bounds__(256, 4) void arc_main(const float* __restrict__ in,
                                                   float* __restrict__ partial) {
  const int row = blockIdx.x * 256 + threadIdx.x;
  float v = 0.0f;
  if (row < kBatch) {
    float x[kNPairs];
    const float4* p = reinterpret_cast<const float4*>(in + (size_t)row * kNPairs);
#pragma unroll
    for (int j = 0; j < 7; ++j) {
      const float4 t = p[j];
      x[4 * j + 0] = t.x;
      x[4 * j + 1] = t.y;
      x[4 * j + 2] = t.z;
      x[4 * j + 3] = t.w;
    }
    // A-part: adjacent pairs live at slots 21..27 (two accumulators for ILP)
    float se0 = 0.0f, se1 = 0.0f;
#pragma unroll
    for (int k = 21; k < 28; ++k) {
      if (k & 1) se0 += __expf(-x[k]); else se1 += __expf(-x[k]);
    }
    // B-part: 219 combinatorial residuals via shared-chain DFS (247 adds total)
    float sa[4] = {0.0f, 0.0f, 0.0f, 0.0f};
    dfs<0, 0, 1, 1>(x, 0.0f, sa);
    dfs<1, 1, 1, 2>(x, 0.0f, sa);
    dfs<2, 2, 1, 3>(x, 0.0f, sa);
    dfs<3, 3, 1, 4>(x, 0.0f, sa);
    dfs<4, 4, 1, 5>(x, 0.0f, sa);
    dfs<5, 5, 1, 6>(x, 0.0f, sa);
    v = (0.5f / 7.0f) * (se0 + se1) +
        (0.5f / 219.0f) * ((sa[0] + sa[1]) + (sa[2] + sa[3]));
  }
  // wave (64-lane) shuffle reduce, then cross-wave LDS reduce
#pragma unroll
  for (int off = 32; off > 0; off >>= 1) v += __shfl_down(v, off, 64);
  __shared__ float red[4];
  const int lane = threadIdx.x & 63;
  const int wid = threadIdx.x >> 6;
  if (lane == 0) red[wid] = v;
  __syncthreads();
  if (threadIdx.x == 0) {
    partial[blockIdx.x] = red[0] + red[1] + red[2] + red[3];
  }
}

__global__ __launch_bounds__(256) void arc_reduce(const float* __restrict__ partial,
                                                  int n, float* __restrict__ out) {
  double v = 0.0;
  for (int i = threadIdx.x; i < n; i += 256) v += (double)partial[i];
#pragma unroll
  for (int off = 32; off > 0; off >>= 1) v += __shfl_down(v, off, 64);
  __shared__ double red[4];
  const int lane = threadIdx.x & 63;
  const int wid = threadIdx.x >> 6;
  if (lane == 0) red[wid] = v;
  __syncthreads();
  if (threadIdx.x == 0) {
    out[0] = (float)((red[0] + red[1] + red[2] + red[3]) / (double)kBatch);
  }
}

}  // namespace

extern "C" void kernel_launch(void* const* d_in, const int* in_sizes, int n_in,
                              void* d_out, int out_size, void* d_ws, size_t ws_size,
                              hipStream_t stream) {
  const float* in = (const float*)d_in[0];
  float* out = (float*)d_out;
  float* partial = (float*)d_ws;  // needs blocks*4 bytes (~7.8 KB)
  const int blocks = (kBatch + 255) / 256;  // 1954
  arc_main<<<blocks, 256, 0, stream>>>(in, partial);
  arc_reduce<<<1, 256, 0, stream>>>(partial, blocks, out);
}

// Round 5
// 19.259 us; speedup vs baseline: 2.3631x; 1.0980x over previous
//
#include <hip/hip_runtime.h>
#include <math.h>

namespace {

constexpr int kN = 8;
constexpr int kBatch = 500000;
constexpr int kNPairs = 28;  // 8*7/2
constexpr int kRowsPerBlock = 512;  // 2 rows/thread
constexpr int kBlocks = (kBatch + kRowsPerBlock - 1) / kRowsPerBlock;  // 977

// Replicates the torch/jax sample_index ordering:
// gaps 2..7 first (each gap g: j=0..N-1-g), then adjacent pairs (j,j+1) at 21..27.
constexpr int pair_index(int a, int b) {
  const int gap = b - a;
  if (gap == 1) return 21 + a;
  int start = 0;
  for (int g = 2; g < gap; ++g) start += kN - g;
  return start + a;
}

// DFS over increasing element sequences. Each extension adds one chain-pair
// value; every sequence of size >= 3 contributes |x[pair(F,last)] - chain|.
// All indices compile-time -> x[] and sa[] stay fully in registers.
// sa[] rotation breaks the serial accumulation chain 4-ways.
template <int F, int LAST, int SIZE, int NEXT>
__device__ __forceinline__ void dfs(const float* x, float chain, float (&sa)[4]) {
  if constexpr (NEXT < kN) {
    const float c2 = chain + x[pair_index(LAST, NEXT)];
    if constexpr (SIZE + 1 >= 3) {
      sa[(F + SIZE + 1) & 3] += fabsf(x[pair_index(F, NEXT)] - c2);
    }
    dfs<F, NEXT, SIZE + 1, NEXT + 1>(x, c2, sa);  // extend through NEXT
    dfs<F, LAST, SIZE, NEXT + 1>(x, chain, sa);   // skip NEXT
  }
}

__device__ __forceinline__ float row_loss(const float* __restrict__ rowp) {
  float x[kNPairs];
  const float4* p = reinterpret_cast<const float4*>(rowp);
#pragma unroll
  for (int j = 0; j < 7; ++j) {
    const float4 t = p[j];
    x[4 * j + 0] = t.x;
    x[4 * j + 1] = t.y;
    x[4 * j + 2] = t.z;
    x[4 * j + 3] = t.w;
  }
  float se0 = 0.0f, se1 = 0.0f;
#pragma unroll
  for (int k = 21; k < 28; ++k) {
    if (k & 1) se0 += __expf(-x[k]); else se1 += __expf(-x[k]);
  }
  float sa[4] = {0.0f, 0.0f, 0.0f, 0.0f};
  dfs<0, 0, 1, 1>(x, 0.0f, sa);
  dfs<1, 1, 1, 2>(x, 0.0f, sa);
  dfs<2, 2, 1, 3>(x, 0.0f, sa);
  dfs<3, 3, 1, 4>(x, 0.0f, sa);
  dfs<4, 4, 1, 5>(x, 0.0f, sa);
  dfs<5, 5, 1, 6>(x, 0.0f, sa);
  return (0.5f / 7.0f) * (se0 + se1) +
         (0.5f / 219.0f) * ((sa[0] + sa[1]) + (sa[2] + sa[3]));
}

// 2 rows/thread: 14 loads in flight, two independent DFS chains interleave
// (2x ILP on the dependent-add chain). (256,4) keeps the ~128-VGPR budget
// that fixed R3's 28-VGPR serialization.
__global__ __launch_bounds__(256, 4) void arc_main(const float* __restrict__ in,
                                                   float* __restrict__ partial) {
  const int tid = threadIdx.x;
  const int base = blockIdx.x * kRowsPerBlock;
  const int r0 = base + tid;
  const int r1 = r0 + 256;
  float v0 = 0.0f, v1 = 0.0f;
  if (r0 < kBatch) v0 = row_loss(in + (size_t)r0 * kNPairs);
  if (r1 < kBatch) v1 = row_loss(in + (size_t)r1 * kNPairs);
  float v = v0 + v1;
#pragma unroll
  for (int off = 32; off > 0; off >>= 1) v += __shfl_down(v, off, 64);
  __shared__ float red[4];
  const int lane = tid & 63;
  const int wid = tid >> 6;
  if (lane == 0) red[wid] = v;
  __syncthreads();
  if (tid == 0) {
    partial[blockIdx.x] = red[0] + red[1] + red[2] + red[3];
  }
}

__global__ __launch_bounds__(256) void arc_reduce(const float* __restrict__ partial,
                                                  int n, float* __restrict__ out) {
  // n = 977: 244 float4 chunks + 1 scalar tail
  const int n4 = n >> 2;
  double v = 0.0;
  const float4* p4 = reinterpret_cast<const float4*>(partial);
  for (int i = threadIdx.x; i < n4; i += 256) {
    const float4 t = p4[i];
    v += (double)t.x + (double)t.y + (double)t.z + (double)t.w;
  }
  for (int i = (n4 << 2) + threadIdx.x; i < n; i += 256) v += (double)partial[i];
#pragma unroll
  for (int off = 32; off > 0; off >>= 1) v += __shfl_down(v, off, 64);
  __shared__ double red[4];
  const int lane = threadIdx.x & 63;
  const int wid = threadIdx.x >> 6;
  if (lane == 0) red[wid] = v;
  __syncthreads();
  if (threadIdx.x == 0) {
    out[0] = (float)((red[0] + red[1] + red[2] + red[3]) / (double)kBatch);
  }
}

}  // namespace

extern "C" void kernel_launch(void* const* d_in, const int* in_sizes, int n_in,
                              void* d_out, int out_size, void* d_ws, size_t ws_size,
                              hipStream_t stream) {
  const float* in = (const float*)d_in[0];
  float* out = (float*)d_out;
  float* partial = (float*)d_ws;  // kBlocks*4 bytes (~3.9 KB)
  arc_main<<<kBlocks, 256, 0, stream>>>(in, partial);
  arc_reduce<<<1, 256, 0, stream>>>(partial, kBlocks, out);
}